// Round 9
// baseline (53.770 us; speedup 1.0000x reference)
//
#include <hip/hip_runtime.h>

#define BIGV 1.0e6f

// ---------------------------------------------------------------------------
// One kernel. Grid: 1024 blocks = (b 0..7) x (dir 0..1) x (patch 0..63).
// 64 threads = 1 wave per block; lane = one query pixel of the 8x8 patch
// (patch == tile of the 8x8 tiling of the 64x64 grid).
// dir 0: m1 = min over (i,j) of pred*(1+d)  [epilogue: gth*m1, (g-p)^2]
// dir 1: m2 = min over (i,j) of gt  *(1+d)  [epilogue: pth*m2]
// Branch & bound over 8x8 tiles: visit in Chebyshev-ring order around the
// patch; evaluate tile only if any lane's bound tmin*(1+dminbox) < m.
// Sound: v >= tmin and d >= dminbox for every pixel in the tile.
// ---------------------------------------------------------------------------
__global__ __launch_bounds__(64) void imageloss_bnb(
    const float* __restrict__ gt, const float* __restrict__ pred,
    float* __restrict__ ws, float* __restrict__ out)
{
    __shared__ float img[4096];
    __shared__ float tmin[64];
    __shared__ int   order[64];
    __shared__ int   cnt9[16];

    const int blk   = blockIdx.x;          // 0..1023
    const int patch = blk & 63;            // query tile id
    const int dir   = (blk >> 6) & 1;
    const int b     = blk >> 7;            // 0..7
    const int lane  = threadIdx.x;         // 0..63

    const float* __restrict__ src = (dir ? gt : pred) + b * 4096;

    // Stage the value image (16 KB) into LDS, coalesced float4.
    #pragma unroll
    for (int k = 0; k < 16; ++k)
        ((float4*)img)[k * 64 + lane] = ((const float4*)src)[k * 64 + lane];
    if (lane < 16) cnt9[lane] = 0;
    __syncthreads();

    // Per-lane tile minimum: lane == tile id (ti, tj).
    const int ti = lane >> 3, tj = lane & 7;
    {
        const float* tp = img + ti * 512 + tj * 8;
        float tv = 1e30f;
        #pragma unroll
        for (int r = 0; r < 8; ++r) {
            float4 a = *(const float4*)(tp + r * 64);
            float4 c = *(const float4*)(tp + r * 64 + 4);
            tv = fminf(tv, fminf(fminf(a.x, a.y), fminf(a.z, a.w)));
            tv = fminf(tv, fminf(fminf(c.x, c.y), fminf(c.z, c.w)));
        }
        tmin[lane] = tv;
    }

    // Ring order: counting-sort tiles by Chebyshev ring around the patch.
    const int Pi = patch >> 3, Pj = patch & 7;
    {
        int dti = ti - Pi; dti = dti < 0 ? -dti : dti;
        int dtj = tj - Pj; dtj = dtj < 0 ? -dtj : dtj;
        const int rho = dti > dtj ? dti : dtj;
        atomicAdd(&cnt9[rho], 1);
        __syncthreads();
        if (lane == 0) {
            int acc = 0;
            #pragma unroll
            for (int r = 0; r < 9; ++r) { int c = cnt9[r]; cnt9[r] = acc; acc += c; }
        }
        __syncthreads();
        const int slot = atomicAdd(&cnt9[rho], 1);
        order[slot] = lane;
    }
    __syncthreads();

    // Per-lane query coordinates.
    const int qi = Pi * 8 + (lane >> 3);
    const int qj = Pj * 8 + (lane & 7);
    const float qif = (float)qi, qjf = (float)qj;

    float ma = 3.4e38f, mb = 3.4e38f;      // dual accumulators for ILP

    for (int s = 0; s < 64; ++s) {
        const int t   = order[s];          // wave-uniform broadcast
        const int tti = t >> 3, ttj = t & 7;
        const float x0 = (float)(tti * 8), x1 = (float)(tti * 8 + 7);
        const float y0 = (float)(ttj * 8), y1 = (float)(ttj * 8 + 7);
        const float dx = fmaxf(fmaxf(x0 - qif, qif - x1), 0.0f);
        const float dy = fmaxf(fmaxf(y0 - qjf, qjf - y1), 0.0f);
        const float dbox = __builtin_amdgcn_sqrtf(fmaf(dx, dx, dy * dy));
        const float tm = tmin[t];
        const float bound = fmaf(tm, dbox, tm);      // tmin*(1+dminbox)
        if (__any(bound < fminf(ma, mb))) {
            const float* tpx = img + tti * 512 + ttj * 8;
            #pragma unroll
            for (int r = 0; r < 8; ++r) {
                const float4 va = *(const float4*)(tpx + r * 64);      // broadcast
                const float4 vb = *(const float4*)(tpx + r * 64 + 4);  // broadcast
                const float pif = (float)(tti * 8 + r);
                const float ddx = qif - pif;
                const float dx2 = ddx * ddx;
                #pragma unroll
                for (int cc = 0; cc < 4; ++cc) {
                    const float pjA = (float)(ttj * 8 + cc);
                    const float pjB = (float)(ttj * 8 + 4 + cc);
                    const float dyA = qjf - pjA;
                    const float dyB = qjf - pjB;
                    const float dA = __builtin_amdgcn_sqrtf(fmaf(dyA, dyA, dx2));
                    const float dB = __builtin_amdgcn_sqrtf(fmaf(dyB, dyB, dx2));
                    const float vA = (&va.x)[cc], vB = (&vb.x)[cc];
                    ma = fminf(ma, fmaf(vA, dA, vA));   // v*(1+d)
                    mb = fminf(mb, fmaf(vB, dB, vB));
                }
            }
        }
    }
    const float m = fminf(ma, mb);

    // Epilogue: per-query contributions, wave-reduce, device atomics.
    const int cell = b * 4096 + qi * 64 + qj;
    const float own = img[qi * 64 + qj];   // staged image value at the query cell

    float c12, sq = 0.0f;
    if (dir == 0) {
        const float g = gt[cell];          // own == pred[cell]
        const float gth = g + (1.0f - g) * BIGV;
        c12 = gth * m;                     // min_dist contribution
        const float df = g - own;
        sq = df * df;                      // loss contribution
    } else {
        const float p = pred[cell];        // own == gt[cell]
        const float pth = p + (1.0f - p) * BIGV;
        c12 = pth * m;                     // min_dist_inv contribution
    }

    #pragma unroll
    for (int off = 32; off > 0; off >>= 1) {
        c12 += __shfl_down(c12, off, 64);
        sq  += __shfl_down(sq,  off, 64);
    }
    if (lane == 0) {
        if (dir == 0) {
            atomicAdd(&ws[0], sq);
            atomicAdd(&ws[1], c12);
        } else {
            atomicAdd(&ws[2], c12);
        }
        __threadfence();
        const int old = atomicAdd((int*)&ws[3], 1);   // ws[3]: counter (memset 0)
        if (old == 1023) {                            // last block finalizes
            const float s0 = atomicAdd(&ws[0], 0.0f); // device-scope coherent reads
            const float s1 = atomicAdd(&ws[1], 0.0f);
            const float s2 = atomicAdd(&ws[2], 0.0f);
            out[0] = s0 * (1.0f / 512.0f);
            out[1] = s1 * (1.0f / 32768.0f);
            out[2] = s2 * (1.0f / 32768.0f);
        }
    }
}

extern "C" void kernel_launch(void* const* d_in, const int* in_sizes, int n_in,
                              void* d_out, int out_size, void* d_ws, size_t ws_size,
                              hipStream_t stream)
{
    const float* gt   = (const float*)d_in[0];
    const float* pred = (const float*)d_in[1];
    float* out = (float*)d_out;
    float* ws  = (float*)d_ws;

    hipMemsetAsync(ws, 0, 4 * sizeof(float), stream);   // ws[0..2] sums, ws[3] counter
    imageloss_bnb<<<1024, 64, 0, stream>>>(gt, pred, ws, out);
}

// Round 10
// 48.736 us; speedup vs baseline: 1.1033x; 1.1033x over previous
//
#include <hip/hip_runtime.h>

#define BIGV 1.0e6f

__device__ __forceinline__ float wave_max64(float v) {
    #pragma unroll
    for (int s = 32; s > 0; s >>= 1)
        v = fmaxf(v, __shfl_xor(v, s, 64));
    return v;
}

// ---------------------------------------------------------------------------
// Grid: 1024 blocks = (b 0..7) x (dir 0..1) x (patch 0..63); 64 thr = 1 wave.
// Lane = one query pixel of the 8x8 patch. Lane ALSO owns tile `lane`'s
// min-value (register) for the lane-parallel bound step.
// dir 0: m1 = min pred*(1+d) [epilogue gth*m1 + (g-p)^2]; dir 1: m2 sym.
// Phase 1: evaluate ring<=1 tiles unconditionally.
// Phase 2: one ballot builds the far-tile need mask from per-lane bounds
//   tmin_l*(1+dbox(patch,tile_l)) < M = wave_max(m); walk nearest-ring-first
//   with re-threshold after each eval. All bounds are sound lower bounds.
// ---------------------------------------------------------------------------
__global__ __launch_bounds__(64) void imageloss_bnb2(
    const float* __restrict__ gt, const float* __restrict__ pred,
    float* __restrict__ ws, float* __restrict__ out)
{
    __shared__ float img[4096];

    const int blk   = blockIdx.x;          // 0..1023
    const int patch = blk & 63;
    const int dir   = (blk >> 6) & 1;
    const int b     = blk >> 7;
    const int lane  = threadIdx.x;         // 0..63

    const float* __restrict__ src = (dir ? gt : pred) + b * 4096;

    // Stage value image (16 KB) into LDS, all 16 loads in flight at once.
    #pragma unroll
    for (int k = 0; k < 16; ++k)
        ((float4*)img)[k * 64 + lane] = ((const float4*)src)[k * 64 + lane];
    __syncthreads();

    // Lane = tile (ti, tj): tile min held in REGISTER (no LDS round-trip).
    const int ti = lane >> 3, tj = lane & 7;
    float tmin_l;
    {
        const float* tp = img + ti * 512 + tj * 8;
        float t0 = 1e30f, t1 = 1e30f;
        #pragma unroll
        for (int r = 0; r < 8; ++r) {
            float4 a = *(const float4*)(tp + r * 64);
            float4 c = *(const float4*)(tp + r * 64 + 4);
            t0 = fminf(t0, fminf(fminf(a.x, a.y), fminf(a.z, a.w)));
            t1 = fminf(t1, fminf(fminf(c.x, c.y), fminf(c.z, c.w)));
        }
        tmin_l = fminf(t0, t1);
    }

    const int Pi = patch >> 3, Pj = patch & 7;
    const int qi = Pi * 8 + (lane >> 3);
    const int qj = Pj * 8 + (lane & 7);
    const float qif = (float)qi, qjf = (float)qj;

    float ma = 3.4e38f, mb = 3.4e38f;      // dual accumulators

    auto eval_tile = [&](int tti, int ttj) {
        const float* tpx = img + tti * 512 + ttj * 8;
        float4 va[8], vb[8];
        #pragma unroll
        for (int r = 0; r < 8; ++r) {      // 16 broadcast b128, one wait window
            va[r] = *(const float4*)(tpx + r * 64);
            vb[r] = *(const float4*)(tpx + r * 64 + 4);
        }
        #pragma unroll
        for (int r = 0; r < 8; ++r) {
            const float ddx = qif - (float)(tti * 8 + r);
            const float dx2 = ddx * ddx;
            #pragma unroll
            for (int cc = 0; cc < 4; ++cc) {
                const float dyA = qjf - (float)(ttj * 8 + cc);
                const float dyB = qjf - (float)(ttj * 8 + 4 + cc);
                const float dA = __builtin_amdgcn_sqrtf(fmaf(dyA, dyA, dx2));
                const float dB = __builtin_amdgcn_sqrtf(fmaf(dyB, dyB, dx2));
                const float vA = (&va[r].x)[cc], vB = (&vb[r].x)[cc];
                ma = fminf(ma, fmaf(vA, dA, vA));   // v*(1+d)
                mb = fminf(mb, fmaf(vB, dB, vB));
            }
        }
    };

    // Phase 1: ring <= 1, unconditional (wave-uniform control flow).
    unsigned long long nearmask = 0;
    #pragma unroll
    for (int di = -1; di <= 1; ++di) {
        #pragma unroll
        for (int dj = -1; dj <= 1; ++dj) {
            const int t2i = Pi + di, t2j = Pj + dj;
            if ((unsigned)t2i < 8u && (unsigned)t2j < 8u) {
                nearmask |= 1ull << (t2i * 8 + t2j);
                eval_tile(t2i, t2j);
            }
        }
    }

    // Lane-parallel far bound: box-to-box distance patch <-> tile(lane).
    int adti = ti - Pi; adti = adti < 0 ? -adti : adti;
    int adtj = tj - Pj; adtj = adtj < 0 ? -adtj : adtj;
    const int rho_l = adti > adtj ? adti : adtj;
    const float gx = fmaxf((float)(adti * 8 - 7), 0.0f);
    const float gy = fmaxf((float)(adtj * 8 - 7), 0.0f);
    const float dbox = __builtin_amdgcn_sqrtf(fmaf(gx, gx, gy * gy));
    const float bnd = fmaf(tmin_l, dbox, tmin_l);   // tmin*(1+dbox)

    float M = wave_max64(fminf(ma, mb));
    unsigned long long remaining = __ballot(bnd < M) & ~nearmask;

    // Walk nearest ring first; re-threshold after every eval (cheap vs eval).
    for (int rho = 2; rho <= 7 && remaining; ++rho) {
        unsigned long long cur = remaining & __ballot(rho_l == rho);
        while (cur) {
            const int t = (int)__builtin_ctzll(cur);
            const unsigned long long bit = 1ull << t;
            cur &= ~bit; remaining &= ~bit;
            eval_tile(t >> 3, t & 7);
            M = wave_max64(fminf(ma, mb));
            const unsigned long long alive = __ballot(bnd < M);
            cur &= alive; remaining &= alive;
        }
    }
    const float m = fminf(ma, mb);

    // Epilogue.
    const int cell = b * 4096 + qi * 64 + qj;
    const float own = img[qi * 64 + qj];

    float c12, sq = 0.0f;
    if (dir == 0) {
        const float g = gt[cell];          // own == pred[cell]
        const float gth = g + (1.0f - g) * BIGV;
        c12 = gth * m;                     // min_dist contribution
        const float df = g - own;
        sq = df * df;                      // loss contribution
    } else {
        const float p = pred[cell];        // own == gt[cell]
        const float pth = p + (1.0f - p) * BIGV;
        c12 = pth * m;                     // min_dist_inv contribution
    }

    #pragma unroll
    for (int off = 32; off > 0; off >>= 1) {
        c12 += __shfl_down(c12, off, 64);
        sq  += __shfl_down(sq,  off, 64);
    }
    if (lane == 0) {
        if (dir == 0) {
            atomicAdd(&ws[0], sq);
            atomicAdd(&ws[1], c12);
        } else {
            atomicAdd(&ws[2], c12);
        }
        __threadfence();
        const int old = atomicAdd((int*)&ws[3], 1);   // counter (memset 0)
        if (old == 1023) {                            // last block finalizes
            const float s0 = atomicAdd(&ws[0], 0.0f);
            const float s1 = atomicAdd(&ws[1], 0.0f);
            const float s2 = atomicAdd(&ws[2], 0.0f);
            out[0] = s0 * (1.0f / 512.0f);
            out[1] = s1 * (1.0f / 32768.0f);
            out[2] = s2 * (1.0f / 32768.0f);
        }
    }
}

extern "C" void kernel_launch(void* const* d_in, const int* in_sizes, int n_in,
                              void* d_out, int out_size, void* d_ws, size_t ws_size,
                              hipStream_t stream)
{
    const float* gt   = (const float*)d_in[0];
    const float* pred = (const float*)d_in[1];
    float* out = (float*)d_out;
    float* ws  = (float*)d_ws;

    hipMemsetAsync(ws, 0, 4 * sizeof(float), stream);
    imageloss_bnb2<<<1024, 64, 0, stream>>>(gt, pred, ws, out);
}

// Round 11
// 47.377 us; speedup vs baseline: 1.1350x; 1.0287x over previous
//
#include <hip/hip_runtime.h>

#define BIGV 1.0e6f

__device__ __forceinline__ float wave_max64(float v) {
    #pragma unroll
    for (int s = 32; s > 0; s >>= 1)
        v = fmaxf(v, __shfl_xor(v, s, 64));
    return v;
}

// ---------------------------------------------------------------------------
// Grid: 1024 blocks = (b 0..7) x (dir 0..1) x (patch 0..63).
// Block: 256 threads = 4 waves, ALL serving the same 8x8 query patch
// (lane = query pixel; the 4 waves split the candidate tiles 4 ways).
//   phase 0: cooperative stage of the value image to LDS.
//   phase 1: ring<=1 tiles round-robin across waves; barrier-combine minima.
//   phase 2: wave v prunes/walks far tiles with t%4==v (per-lane sound bound
//            tmin_l*(1+dbox) vs evolving wave threshold), nearest-ring first.
//   phase 3: barrier-combine; wave 0 does epilogue + device-atomic finalize.
// 4096 waves total -> 4 waves/SIMD: latency from LDS/shfl/ballot is hidden
// by cross-wave issue instead of being exposed (R10: 1 wave/SIMD, VALU 11%).
// ---------------------------------------------------------------------------
__global__ __launch_bounds__(256) void imageloss_bnb3(
    const float* __restrict__ gt, const float* __restrict__ pred,
    float* __restrict__ ws, float* __restrict__ out)
{
    __shared__ float img[4096];
    __shared__ float red[4][64];

    const int blk   = blockIdx.x;          // 0..1023
    const int patch = blk & 63;
    const int dir   = (blk >> 6) & 1;
    const int b     = blk >> 7;
    const int tid   = threadIdx.x;
    const int wv    = tid >> 6;            // wave 0..3
    const int lane  = tid & 63;

    const float* __restrict__ src = (dir ? gt : pred) + b * 4096;

    // Phase 0: stage the 16 KB value image, 256 threads x 4 float4.
    #pragma unroll
    for (int k = 0; k < 4; ++k)
        ((float4*)img)[k * 256 + tid] = ((const float4*)src)[k * 256 + tid];
    __syncthreads();

    // Per-lane tile min (lane == tile id), per-wave register copy.
    const int ti = lane >> 3, tj = lane & 7;
    float tmin_l;
    {
        const float* tp = img + ti * 512 + tj * 8;
        float t0 = 1e30f, t1 = 1e30f;
        #pragma unroll
        for (int r = 0; r < 8; ++r) {
            float4 a = *(const float4*)(tp + r * 64);
            float4 c = *(const float4*)(tp + r * 64 + 4);
            t0 = fminf(t0, fminf(fminf(a.x, a.y), fminf(a.z, a.w)));
            t1 = fminf(t1, fminf(fminf(c.x, c.y), fminf(c.z, c.w)));
        }
        tmin_l = fminf(t0, t1);
    }

    const int Pi = patch >> 3, Pj = patch & 7;
    const int qi = Pi * 8 + ti;            // lane's query pixel
    const int qj = Pj * 8 + tj;
    const float qif = (float)qi, qjf = (float)qj;

    float ma = 3.4e38f, mb = 3.4e38f;      // dual accumulators

    auto eval_tile = [&](int tti, int ttj) {
        const float* tpx = img + tti * 512 + ttj * 8;
        float4 va[8], vb[8];
        #pragma unroll
        for (int r = 0; r < 8; ++r) {      // 16 broadcast b128, one wait window
            va[r] = *(const float4*)(tpx + r * 64);
            vb[r] = *(const float4*)(tpx + r * 64 + 4);
        }
        #pragma unroll
        for (int r = 0; r < 8; ++r) {
            const float ddx = qif - (float)(tti * 8 + r);
            const float dx2 = ddx * ddx;
            #pragma unroll
            for (int cc = 0; cc < 4; ++cc) {
                const float dyA = qjf - (float)(ttj * 8 + cc);
                const float dyB = qjf - (float)(ttj * 8 + 4 + cc);
                const float dA = __builtin_amdgcn_sqrtf(fmaf(dyA, dyA, dx2));
                const float dB = __builtin_amdgcn_sqrtf(fmaf(dyB, dyB, dx2));
                const float vA = (&va[r].x)[cc], vB = (&vb[r].x)[cc];
                ma = fminf(ma, fmaf(vA, dA, vA));   // v*(1+d)
                mb = fminf(mb, fmaf(vB, dB, vB));
            }
        }
    };

    // Phase 1: ring <= 1 tiles, round-robin across the 4 waves.
    unsigned long long nearmask = 0;
    int nidx = 0;
    #pragma unroll
    for (int di = -1; di <= 1; ++di) {
        #pragma unroll
        for (int dj = -1; dj <= 1; ++dj) {
            const int t2i = Pi + di, t2j = Pj + dj;
            if ((unsigned)t2i < 8u && (unsigned)t2j < 8u) {
                nearmask |= 1ull << (t2i * 8 + t2j);
                if ((nidx & 3) == wv) eval_tile(t2i, t2j);
                ++nidx;
            }
        }
    }

    // Combine phase-1 partial minima across the 4 waves.
    red[wv][lane] = fminf(ma, mb);
    __syncthreads();
    const float mcomb = fminf(fminf(red[0][lane], red[1][lane]),
                              fminf(red[2][lane], red[3][lane]));
    ma = mcomb; mb = 3.4e38f;

    // Per-lane far bound: box-to-box distance patch <-> tile(lane).
    int adti = ti - Pi; adti = adti < 0 ? -adti : adti;
    int adtj = tj - Pj; adtj = adtj < 0 ? -adtj : adtj;
    const int rho_l = adti > adtj ? adti : adtj;
    const float gx = fmaxf((float)(adti * 8 - 7), 0.0f);
    const float gy = fmaxf((float)(adtj * 8 - 7), 0.0f);
    const float dbox = __builtin_amdgcn_sqrtf(fmaf(gx, gx, gy * gy));
    const float bnd = fmaf(tmin_l, dbox, tmin_l);   // tmin*(1+dbox), sound

    // Wave v owns tiles with t % 4 == v.
    const unsigned long long wavesel = 0x1111111111111111ull << wv;
    float M = wave_max64(ma);
    unsigned long long remaining = __ballot(bnd < M) & ~nearmask & wavesel;

    for (int rho = 2; rho <= 7 && remaining; ++rho) {
        unsigned long long cur = remaining & __ballot(rho_l == rho);
        while (cur) {
            const int t = (int)__builtin_ctzll(cur);
            const unsigned long long bit = 1ull << t;
            cur &= ~bit; remaining &= ~bit;
            eval_tile(t >> 3, t & 7);
            M = wave_max64(fminf(ma, mb));
            const unsigned long long alive = __ballot(bnd < M);
            cur &= alive; remaining &= alive;
        }
    }

    // Phase 3: final combine; wave 0 runs the epilogue.
    red[wv][lane] = fminf(ma, mb);
    __syncthreads();

    if (wv == 0) {
        const float m = fminf(fminf(red[0][lane], red[1][lane]),
                              fminf(red[2][lane], red[3][lane]));

        const int cell = b * 4096 + qi * 64 + qj;
        const float own = img[qi * 64 + qj];

        float c12, sq = 0.0f;
        if (dir == 0) {
            const float g = gt[cell];          // own == pred[cell]
            const float gth = g + (1.0f - g) * BIGV;
            c12 = gth * m;                     // min_dist contribution
            const float df = g - own;
            sq = df * df;                      // loss contribution
        } else {
            const float p = pred[cell];        // own == gt[cell]
            const float pth = p + (1.0f - p) * BIGV;
            c12 = pth * m;                     // min_dist_inv contribution
        }

        #pragma unroll
        for (int off = 32; off > 0; off >>= 1) {
            c12 += __shfl_down(c12, off, 64);
            sq  += __shfl_down(sq,  off, 64);
        }
        if (lane == 0) {
            if (dir == 0) {
                atomicAdd(&ws[0], sq);
                atomicAdd(&ws[1], c12);
            } else {
                atomicAdd(&ws[2], c12);
            }
            __threadfence();
            const int old = atomicAdd((int*)&ws[3], 1);   // counter (memset 0)
            if (old == 1023) {                            // last block finalizes
                const float s0 = atomicAdd(&ws[0], 0.0f);
                const float s1 = atomicAdd(&ws[1], 0.0f);
                const float s2 = atomicAdd(&ws[2], 0.0f);
                out[0] = s0 * (1.0f / 512.0f);
                out[1] = s1 * (1.0f / 32768.0f);
                out[2] = s2 * (1.0f / 32768.0f);
            }
        }
    }
}

extern "C" void kernel_launch(void* const* d_in, const int* in_sizes, int n_in,
                              void* d_out, int out_size, void* d_ws, size_t ws_size,
                              hipStream_t stream)
{
    const float* gt   = (const float*)d_in[0];
    const float* pred = (const float*)d_in[1];
    float* out = (float*)d_out;
    float* ws  = (float*)d_ws;

    hipMemsetAsync(ws, 0, 4 * sizeof(float), stream);
    imageloss_bnb3<<<1024, 256, 0, stream>>>(gt, pred, ws, out);
}